// Round 2
// baseline (408.610 us; speedup 1.0000x reference)
//
#include <hip/hip_runtime.h>

// LocallyConnected2d: out[b,o,h,w] = sum_{c,k} x[b,c,h+kh-1,w+kw-1] * wgt[o,c,h,w,k]
// B=8 C=32 O=64 H=W=64 K=9 (kh-major). fp32 in / fp32 out (per reference; the R1
// NaN proved the buffers are fp32 — bf16 reinterpretation produced NaN patterns).
//
// Memory-bound on the 302 MB fp32 weight stream (read exactly once).
// - thread = (w=lane, o-pair), holds all 8 batch accumulators -> weight read 1x, used 8x
// - x staged per-c into LDS as two stride-16 float4 planes (batches 0-3 / 4-7):
//   ds_read_b128 in the lane-contiguous conflict-free pattern, 2 reads per (dh,dw)
//   position serve 16 FMAs
// - 512 blocks (h x o-octet) x 256 thr = 2 blocks/CU, 8 waves/CU; LDS double-buffered,
//   next-c weights + stage prefetched into registers; 1 barrier per c-iter.

#define BB 8
#define CC 32
#define OO 64
#define HH 64
#define WW 64
#define KK 9
#define CHW (CC * HH * WW)   // x batch stride  (131072)
#define OHW (HH * WW)        // x channel stride (4096)
#define WCS (HH * WW * KK)   // wgt channel stride (36864)
#define WOS (CC * HH * WW * KK) // wgt o stride (1179648)

__global__ __launch_bounds__(256, 2)
void lc2d_kernel(const float* __restrict__ x,
                 const float* __restrict__ wgt,
                 float* __restrict__ out)
{
  const int tid  = threadIdx.x;
  const int w    = tid & 63;
  const int osub = tid >> 6;          // 0..3
  const int h    = blockIdx.x & 63;
  const int og   = blockIdx.x >> 6;   // 0..7
  const int o0   = og * 8 + osub * 2; // this thread: o0, o0+1

  // LDS x tile for one c: [buf][half(b0-3|b4-7)][ (dh*66 + w') ], float4 per entry.
  // Stride-16 lane-contiguous reads -> conflict-free ds_read_b128.
  __shared__ float4 xs[2][2][198];

  // ---- staging coords (threads 0..197 stage one (dh,w') position, all 8 b) ----
  const int p   = tid;
  const int dh  = (p >= 132) ? 2 : ((p >= 66) ? 1 : 0);
  const int wpp = p - dh * 66;
  const int r   = h + dh - 1;
  const int col = wpp - 1;
  const bool sactive = (p < 198);
  const bool svalid  = sactive && (r >= 0) && (r < HH) && (col >= 0) && (col < WW);
  const int xoff0 = r * WW + col;     // + c*OHW + b*CHW

  // ---- weight pointers: elem = (((o*CC + c)*HH + h)*WW + w)*KK + k ----
  const float* wq0 = wgt + (o0 * CC * HH + h) * (WW * KK) + w * KK;
  const float* wq1 = wq0 + WOS;       // o0+1

  float acc[2][8];
#pragma unroll
  for (int j = 0; j < 2; ++j)
#pragma unroll
    for (int b = 0; b < 8; ++b) acc[j][b] = 0.f;

  auto load_stage = [&](int c, float4& lo, float4& hi) {
    lo = make_float4(0.f, 0.f, 0.f, 0.f);
    hi = make_float4(0.f, 0.f, 0.f, 0.f);
    if (svalid) {
      const float* q = x + (xoff0 + c * OHW);
      lo.x = q[0 * CHW]; lo.y = q[1 * CHW]; lo.z = q[2 * CHW]; lo.w = q[3 * CHW];
      hi.x = q[4 * CHW]; hi.y = q[5 * CHW]; hi.z = q[6 * CHW]; hi.w = q[7 * CHW];
    }
  };

  auto load_w = [&](int c, float (&wrr)[2][KK]) {
    const float* a = wq0 + c * WCS;
    const float* b = wq1 + c * WCS;
#pragma unroll
    for (int k = 0; k < KK; ++k) { wrr[0][k] = a[k]; wrr[1][k] = b[k]; }
  };

  auto compute = [&](int cur, const float (&wrr)[2][KK]) {
    float4 plo[KK], phi[KK];
#pragma unroll
    for (int d = 0; d < 3; ++d)
#pragma unroll
      for (int e = 0; e < 3; ++e) {
        plo[d * 3 + e] = xs[cur][0][d * 66 + w + e];
        phi[d * 3 + e] = xs[cur][1][d * 66 + w + e];
      }
#pragma unroll
    for (int k = 0; k < KK; ++k) {
      float xf[8];
      xf[0] = plo[k].x; xf[1] = plo[k].y; xf[2] = plo[k].z; xf[3] = plo[k].w;
      xf[4] = phi[k].x; xf[5] = phi[k].y; xf[6] = phi[k].z; xf[7] = phi[k].w;
#pragma unroll
      for (int j = 0; j < 2; ++j) {
        const float wf = wrr[j][k];
#pragma unroll
        for (int b = 0; b < 8; ++b)
          acc[j][b] = fmaf(wf, xf[b], acc[j][b]);
      }
    }
  };

  // ---- prologue: stage c=0, prefetch weights c=0 ----
  float4 slo, shi;
  load_stage(0, slo, shi);
  float wr[2][KK];
  load_w(0, wr);
  if (sactive) { xs[0][0][p] = slo; xs[0][1][p] = shi; }
  __syncthreads();

  // ---- main loop: compute c, prefetch+stage c+1, one barrier per iter ----
  for (int c = 0; c < CC - 1; ++c) {
    float4 nlo, nhi;
    load_stage(c + 1, nlo, nhi);
    float wn[2][KK];
    load_w(c + 1, wn);

    compute(c & 1, wr);

    if (sactive) { xs[(c + 1) & 1][0][p] = nlo; xs[(c + 1) & 1][1][p] = nhi; }
#pragma unroll
    for (int k = 0; k < KK; ++k) { wr[0][k] = wn[0][k]; wr[1][k] = wn[1][k]; }
    __syncthreads();
  }
  compute((CC - 1) & 1, wr);

  // ---- epilogue: out[b,o,h,w], lane-consecutive in w -> coalesced ----
#pragma unroll
  for (int j = 0; j < 2; ++j) {
    const int o = o0 + j;
#pragma unroll
    for (int b = 0; b < 8; ++b)
      out[((b * OO + o) * HH + h) * WW + w] = acc[j][b];
  }
}

extern "C" void kernel_launch(void* const* d_in, const int* in_sizes, int n_in,
                              void* d_out, int out_size, void* d_ws, size_t ws_size,
                              hipStream_t stream) {
  const float* x   = (const float*)d_in[0];
  const float* wgt = (const float*)d_in[1];
  float* out       = (float*)d_out;
  (void)in_sizes; (void)n_in; (void)out_size; (void)d_ws; (void)ws_size;
  lc2d_kernel<<<dim3(HH * (OO / 8)), dim3(256), 0, stream>>>(x, wgt, out);
}